// Round 1
// baseline (20387.158 us; speedup 1.0000x reference)
//
#include <hip/hip_runtime.h>
#include <hip/hip_cooperative_groups.h>

namespace cg = cooperative_groups;

#define NB 128
#define NS 256
#define ND 1024
#define NH 1024
#define NT 20
#define NG 4096
#define START_IDX_ 19

typedef __bf16 v8bf __attribute__((ext_vector_type(8)));
typedef float v4f __attribute__((ext_vector_type(4)));

static __device__ __forceinline__ unsigned short f2bf(float f){
  union { float f; unsigned u; } v; v.f = f;
  unsigned r = v.u + 0x7fffu + ((v.u >> 16) & 1u);
  return (unsigned short)(r >> 16);
}
static __device__ __forceinline__ float bf2f(unsigned short h){
  union { unsigned u; float f; } v; v.u = ((unsigned)h) << 16; return v.f;
}
static __device__ __forceinline__ float sigm(float x){ return 1.0f / (1.0f + __expf(-x)); }
static __device__ __forceinline__ float tanhf_(float x){ return 1.0f - 2.0f / (__expf(2.0f * x) + 1.0f); }

typedef __attribute__((address_space(1))) const unsigned int gu32_t;
typedef __attribute__((address_space(3))) unsigned int lu32_t;
static __device__ __forceinline__ void gload16(const void* g, void* l){
  __builtin_amdgcn_global_load_lds((gu32_t*)g, (lu32_t*)l, 16, 0, 0);
}
static __device__ __forceinline__ v4f mfma16x16x32(v8bf a, v8bf b, v4f c){
  return __builtin_amdgcn_mfma_f32_16x16x32_bf16(a, b, c, 0, 0, 0);
}

// ---------------- prep kernels ----------------

// One block per permuted gate row j' = k*4 + g  (g in i,f,g,o order).
__global__ void k_prep_w(const float* __restrict__ Wih, const float* __restrict__ Whh_in,
                         unsigned short* __restrict__ Wx, unsigned short* __restrict__ Whh){
  int jp = blockIdx.x;
  int g = jp & 3, kr = jp >> 2;
  int j = g * NH + kr;
  int k = threadIdx.x * 4;
  float4 a = *(const float4*)(Wih + (size_t)j * (ND + NT) + k);
  float4 b = *(const float4*)(Whh_in + ((size_t)j << 10) + k);
  unsigned short* d1 = Wx + ((size_t)jp << 10) + k;
  unsigned short* d2 = Whh + ((size_t)jp << 10) + k;
  d1[0] = f2bf(a.x); d1[1] = f2bf(a.y); d1[2] = f2bf(a.z); d1[3] = f2bf(a.w);
  d2[0] = f2bf(b.x); d2[1] = f2bf(b.y); d2[2] = f2bf(b.z); d2[3] = f2bf(b.w);
}

__global__ void k_prep_tb(const float* __restrict__ Wih, const float* __restrict__ bih,
                          const float* __restrict__ bhh, float* __restrict__ Wtag,
                          float* __restrict__ biasc){
  int blk = blockIdx.x;
  for (int jp = threadIdx.x; jp < NG; jp += 256){
    int g = jp & 3, kr = jp >> 2;
    int j = g * NH + kr;
    if (blk < NT) Wtag[(size_t)blk * NG + jp] = Wih[(size_t)j * (ND + NT) + ND + blk];
    else          biasc[jp] = bih[j] + bhh[j];
  }
}

__global__ void k_prep_state(float* c, float* hf, unsigned short* hb0, unsigned short* hb1,
                             int* ptag, float* loss){
  int i = blockIdx.x * 256 + threadIdx.x;   // grid covers 131072
  c[i] = 0.f; hf[i] = 0.f; hb0[i] = 0; hb1[i] = 0;
  if (i < NB) ptag[i] = START_IDX_;
  if (i == 0) *loss = 0.f;
}

// x[b][s][d] f32 -> xb[(s*128+b)][d] bf16
__global__ void k_xpose(const float* __restrict__ x, unsigned short* __restrict__ xb){
  int r = blockIdx.x;
  int b = r & 127, s = r >> 7;
  int d = threadIdx.x * 4;
  float4 v = *(const float4*)(x + (((size_t)b * NS + s) << 10) + d);
  unsigned short* o = xb + ((size_t)r << 10) + d;
  o[0] = f2bf(v.x); o[1] = f2bf(v.y); o[2] = f2bf(v.z); o[3] = f2bf(v.w);
}

// ---------------- Gx precompute GEMM ----------------
// Gx[r][j'] = sum_k xb[row0+r][k] * Wx[j'][k]   (128x128 tile, BK=32, global_load_lds)
__global__ __launch_bounds__(256, 2) void k_gemm_gx(const unsigned short* __restrict__ xb,
                                                    const unsigned short* __restrict__ Wx,
                                                    unsigned short* __restrict__ Gx, int row0){
  __shared__ unsigned short At[128 * 32];
  __shared__ unsigned short Bt[128 * 32];
  const int tid = threadIdx.x;
  const int wave = tid >> 6, lane = tid & 63;
  const int l15 = lane & 15, l4 = lane >> 4;
  const int wm = wave >> 1, wn = wave & 1;
  const int mloc = (int)blockIdx.x * 128;
  const int n0 = (int)blockIdx.y * 128;
  const unsigned short* Ab = xb + ((size_t)(row0 + mloc) << 10);
  const unsigned short* Bb = Wx + ((size_t)n0 << 10);

  v4f acc[4][4];
#pragma unroll
  for (int i = 0; i < 4; ++i)
#pragma unroll
    for (int j = 0; j < 4; ++j) acc[i][j] = (v4f){0.f, 0.f, 0.f, 0.f};

  for (int kk = 0; kk < 32; ++kk){
    const int k0 = kk * 32;
#pragma unroll
    for (int is = 0; is < 2; ++is){
      int c = is * 256 + tid;
      gload16(Ab + ((size_t)(c >> 2) << 10) + k0 + (c & 3) * 8, At + (is * 256 + wave * 64) * 8);
      gload16(Bb + ((size_t)(c >> 2) << 10) + k0 + (c & 3) * 8, Bt + (is * 256 + wave * 64) * 8);
    }
    __syncthreads();
    v8bf af[4], bfm[4];
#pragma unroll
    for (int i = 0; i < 4; ++i) af[i]  = *(const v8bf*)(At + (wm * 64 + i * 16 + l15) * 32 + l4 * 8);
#pragma unroll
    for (int j = 0; j < 4; ++j) bfm[j] = *(const v8bf*)(Bt + (wn * 64 + j * 16 + l15) * 32 + l4 * 8);
#pragma unroll
    for (int i = 0; i < 4; ++i)
#pragma unroll
      for (int j = 0; j < 4; ++j) acc[i][j] = mfma16x16x32(af[i], bfm[j], acc[i][j]);
    __syncthreads();
  }
#pragma unroll
  for (int i = 0; i < 4; ++i)
#pragma unroll
    for (int j = 0; j < 4; ++j){
      int r = mloc + wm * 64 + i * 16 + l4 * 4;
      int cc = n0 + wn * 64 + j * 16 + l15;
#pragma unroll
      for (int q = 0; q < 4; ++q) Gx[((size_t)(r + q) << 12) + cc] = f2bf(acc[i][j][q]);
    }
}

// ---------------- persistent cooperative step kernel ----------------

struct StepArgs {
  const unsigned short* Whh;   // [4096][1024] bf16 permuted
  const unsigned short* Gx;    // [nsteps*128][4096] bf16 (chunk-local)
  const float* Wtag;           // [20][4096]
  const float* biasc;          // [4096]
  const float* Wout;           // [20][1024] f32 (d_in)
  const float* bout;           // [20]
  const int* tags;             // [128][256]
  const int* mask;             // [128][256]
  unsigned short* hb0;         // [128][1024] bf16 (parity 0)
  unsigned short* hb1;         // parity 1
  float* hf;                   // [128][1024] f32 (latest h)
  float* c;                    // [128][1024] f32
  int* ptag;                   // [128]
  float* loss;                 // scalar
  int s0;
  int nsteps;
};

// 256 wgs (1/CU), 512 threads. wg tile: 32 batch rows x 64 gate cols, K=1024.
__global__ __launch_bounds__(512, 1) void k_step(StepArgs A){
  __shared__ unsigned short Wsl[64 * 1024];   // 128 KB persistent W_hh slice
  cg::grid_group grid = cg::this_grid();
  const int tid = threadIdx.x;
  const int wave = tid >> 6, lane = tid & 63;
  const int l15 = lane & 15, l4 = lane >> 4;
  const int wm = wave >> 2, wn = wave & 3;
  const int b0 = ((int)blockIdx.x >> 6) * 32;
  const int n0 = ((int)blockIdx.x & 63) * 64;

  // load Whh slice into LDS once, XOR-swizzled (write & read use same involution)
  for (int ch = tid; ch < 64 * 128; ch += 512){
    int jl = ch >> 7, kc = ch & 127;
    v8bf v = *(const v8bf*)(A.Whh + ((size_t)(n0 + jl) << 10) + kc * 8);
    *(v8bf*)((char*)Wsl + ((size_t)jl << 11) +
             (((unsigned)(kc << 4)) ^ ((unsigned)((jl & 7) << 4)))) = v;
  }
  __syncthreads();

  const int jl_f = wn * 16 + l15;
  const char* wbase = (const char*)Wsl + ((size_t)jl_f << 11);
  const unsigned sw = (unsigned)((jl_f & 7) << 4);
  const int jcol = n0 + jl_f;
  const int kh = jcol >> 2;
  const int bb = b0 + wm * 16 + l4 * 4;
  const float gb = A.biasc[jcol];
  const int qb = lane & ~3;

  for (int sl = 0; sl < A.nsteps; ++sl){
    const int s = A.s0 + sl;
    const unsigned short* hr = (s & 1) ? A.hb1 : A.hb0;
    unsigned short* hw = (s & 1) ? A.hb0 : A.hb1;

    // ---- phase 1: gates = h @ Whh^T (+Gx +bias +tag), update c/h ----
    v4f acc = {0.f, 0.f, 0.f, 0.f};
    const unsigned short* hrow = hr + ((size_t)(b0 + wm * 16 + l15) << 10) + l4 * 8;
#pragma unroll 4
    for (int kk = 0; kk < 32; ++kk){
      v8bf a = *(const v8bf*)(hrow + kk * 32);
      v8bf b = *(const v8bf*)(wbase + (((unsigned)(kk * 64 + l4 * 16)) ^ sw));
      acc = mfma16x16x32(a, b, acc);
    }
    const unsigned short* gxs = A.Gx + (size_t)sl * NB * NG + jcol;
    float gv[4];
#pragma unroll
    for (int q = 0; q < 4; ++q){
      int bq = bb + q;
      int pt = A.ptag[bq];
      gv[q] = acc[q] + gb + bf2f(gxs[(size_t)bq * NG]) + A.Wtag[(size_t)pt * NG + jcol];
    }
#pragma unroll
    for (int q = 0; q < 4; ++q){
      float iv = __shfl(gv[q], qb + 0);
      float fv = __shfl(gv[q], qb + 1);
      float gg = __shfl(gv[q], qb + 2);
      float ov = __shfl(gv[q], qb + 3);
      if ((lane & 3) == 0){
        int bq = bb + q;
        size_t off = ((size_t)bq << 10) + kh;
        float cn = sigm(fv) * A.c[off] + sigm(iv) * tanhf_(gg);
        float hn = sigm(ov) * tanhf_(cn);
        A.c[off] = cn;
        A.hf[off] = hn;
        hw[off] = f2bf(hn);
      }
    }
    grid.sync();   // h complete

    // ---- phase 2: logits, argmax, NLL (32 wgs x 4 rows) ----
    if (blockIdx.x < 32 && wave < 4){
      int b = (int)blockIdx.x * 4 + wave;
      const float* hrowf = A.hf + ((size_t)b << 10);
      float p[NT];
#pragma unroll
      for (int t = 0; t < NT; ++t) p[t] = 0.f;
#pragma unroll
      for (int kc = 0; kc < 4; ++kc){
        int k = lane * 16 + kc * 4;
        float4 hv = *(const float4*)(hrowf + k);
#pragma unroll
        for (int t = 0; t < NT; ++t){
          float4 wv = *(const float4*)(A.Wout + t * NH + k);
          p[t] += hv.x * wv.x + hv.y * wv.y + hv.z * wv.z + hv.w * wv.w;
        }
      }
#pragma unroll
      for (int t = 0; t < NT; ++t){
        float v = p[t];
        v += __shfl_xor(v, 1);  v += __shfl_xor(v, 2);  v += __shfl_xor(v, 4);
        v += __shfl_xor(v, 8);  v += __shfl_xor(v, 16); v += __shfl_xor(v, 32);
        p[t] = v;
      }
      int tg = A.tags[(size_t)b * NS + s];
      int mk = A.mask[(size_t)b * NS + s];
      float m = -1e30f; int am = 0; float ytv = 0.f;
#pragma unroll
      for (int t = 0; t < NT; ++t){
        float v = p[t] + A.bout[t];
        p[t] = v;
        if (v > m){ m = v; am = t; }     // strict > : first max, matches jnp.argmax
        if (t == tg) ytv = v;
      }
      float se = 0.f;
#pragma unroll
      for (int t = 0; t < NT; ++t) se += __expf(p[t] - m);
      float lse = m + __logf(se);
      if (lane == 0){
        A.ptag[b] = am;
        if (mk != 0) atomicAdd(A.loss, lse - ytv);
      }
    }
    grid.sync();   // prev_tag complete
  }
}

__global__ void k_final(const float* loss, float* out){ out[0] = *loss; }

// ---------------- host ----------------

extern "C" void kernel_launch(void* const* d_in, const int* in_sizes, int n_in,
                              void* d_out, int out_size, void* d_ws, size_t ws_size,
                              hipStream_t stream){
  const float* x      = (const float*)d_in[0];
  const int*   tags   = (const int*)  d_in[1];
  const int*   mask   = (const int*)  d_in[2];
  const float* Wih    = (const float*)d_in[3];
  const float* Whh_in = (const float*)d_in[4];
  const float* bih    = (const float*)d_in[5];
  const float* bhh    = (const float*)d_in[6];
  const float* Wout   = (const float*)d_in[7];
  const float* bout   = (const float*)d_in[8];

  char* base = (char*)d_ws;
  size_t off = 0;
  auto alloc = [&](size_t bytes) -> char* {
    char* p = base + off;
    off = (off + bytes + 255) & ~(size_t)255;
    return p;
  };
  unsigned short* Wx    = (unsigned short*)alloc((size_t)NG * NH * 2);
  unsigned short* Whh   = (unsigned short*)alloc((size_t)NG * NH * 2);
  float*          Wtag  = (float*)alloc((size_t)NT * NG * 4);
  float*          biasc = (float*)alloc((size_t)NG * 4);
  unsigned short* hb0   = (unsigned short*)alloc((size_t)NB * NH * 2);
  unsigned short* hb1   = (unsigned short*)alloc((size_t)NB * NH * 2);
  float*          hf    = (float*)alloc((size_t)NB * NH * 4);
  float*          c     = (float*)alloc((size_t)NB * NH * 4);
  int*            ptag  = (int*)alloc(NB * 4);
  float*          loss  = (float*)alloc(256);
  unsigned short* xb    = (unsigned short*)alloc((size_t)NS * NB * NH * 2);

  size_t fixed = off;
  int schunk = NS;
  while (schunk > 1 && fixed + (size_t)schunk * NB * NG * 2 > ws_size) schunk >>= 1;
  unsigned short* Gx = (unsigned short*)alloc((size_t)schunk * NB * NG * 2);

  k_prep_w<<<NG, 256, 0, stream>>>(Wih, Whh_in, Wx, Whh);
  k_prep_tb<<<NT + 1, 256, 0, stream>>>(Wih, bih, bhh, Wtag, biasc);
  k_prep_state<<<(NB * NH) / 256, 256, 0, stream>>>(c, hf, hb0, hb1, ptag, loss);
  k_xpose<<<NS * NB, 256, 0, stream>>>(x, xb);

  int done = 0;
  while (done < NS){
    int ns = (NS - done < schunk) ? (NS - done) : schunk;
    k_gemm_gx<<<dim3(ns, 32), 256, 0, stream>>>(xb, Wx, Gx, done * NB);
    StepArgs sa;
    sa.Whh = Whh; sa.Gx = Gx; sa.Wtag = Wtag; sa.biasc = biasc;
    sa.Wout = Wout; sa.bout = bout; sa.tags = tags; sa.mask = mask;
    sa.hb0 = hb0; sa.hb1 = hb1; sa.hf = hf; sa.c = c;
    sa.ptag = ptag; sa.loss = loss; sa.s0 = done; sa.nsteps = ns;
    void* kargs[] = { &sa };
    hipLaunchCooperativeKernel((void*)k_step, dim3(256), dim3(512), kargs, 0, stream);
    done += ns;
  }
  k_final<<<1, 1, 0, stream>>>(loss, (float*)d_out);
}

// Round 2
// 7566.869 us; speedup vs baseline: 2.6943x; 2.6943x over previous
//
#include <hip/hip_runtime.h>

#define NB 128
#define NS 256
#define ND 1024
#define NH 1024
#define NT 20
#define NG 4096
#define START_IDX_ 19
#define NBLK 256u

typedef __bf16 v8bf __attribute__((ext_vector_type(8)));
typedef float v4f __attribute__((ext_vector_type(4)));

static __device__ __forceinline__ unsigned short f2bf(float f){
  union { float f; unsigned u; } v; v.f = f;
  unsigned r = v.u + 0x7fffu + ((v.u >> 16) & 1u);
  return (unsigned short)(r >> 16);
}
static __device__ __forceinline__ float bf2f(unsigned short h){
  union { unsigned u; float f; } v; v.u = ((unsigned)h) << 16; return v.f;
}
static __device__ __forceinline__ float sigm(float x){ return 1.0f / (1.0f + __expf(-x)); }
static __device__ __forceinline__ float tanhf_(float x){ return 1.0f - 2.0f / (__expf(2.0f * x) + 1.0f); }

typedef __attribute__((address_space(1))) const unsigned int gu32_t;
typedef __attribute__((address_space(3))) unsigned int lu32_t;
static __device__ __forceinline__ void gload16(const void* g, void* l){
  __builtin_amdgcn_global_load_lds((gu32_t*)g, (lu32_t*)l, 16, 0, 0);
}
static __device__ __forceinline__ v4f mfma16x16x32(v8bf a, v8bf b, v4f c){
  return __builtin_amdgcn_mfma_f32_16x16x32_bf16(a, b, c, 0, 0, 0);
}

// ---- hierarchical grid barrier (monotone counters, no reset) ----
// layout (u32 words, 64B apart): xcnt[x] @ x*16, gcnt @ 128, xrel[x] @ (16+x)*16
static __device__ __forceinline__ void gridbar(unsigned* bar, unsigned e){
  __syncthreads();
  if (threadIdx.x == 0){
    unsigned x = (unsigned)blockIdx.x & 7u;
    unsigned old = __hip_atomic_fetch_add(bar + x * 16, 1u, __ATOMIC_ACQ_REL, __HIP_MEMORY_SCOPE_AGENT);
    if (old == 32u * e - 1u){
      unsigned g = __hip_atomic_fetch_add(bar + 128, 1u, __ATOMIC_ACQ_REL, __HIP_MEMORY_SCOPE_AGENT);
      if (g == 8u * e - 1u){
#pragma unroll
        for (unsigned x2 = 0; x2 < 8; ++x2)
          __hip_atomic_store(bar + (16u + x2) * 16, e, __ATOMIC_RELEASE, __HIP_MEMORY_SCOPE_AGENT);
      }
    }
    while (__hip_atomic_load(bar + (16u + x) * 16, __ATOMIC_RELAXED, __HIP_MEMORY_SCOPE_AGENT) < e)
      __builtin_amdgcn_s_sleep(2);
    (void)__hip_atomic_load(bar + (16u + x) * 16, __ATOMIC_ACQUIRE, __HIP_MEMORY_SCOPE_AGENT);
  }
  __syncthreads();
}

// ---------------- prep kernels ----------------

__global__ void k_prep_w(const float* __restrict__ Wih, const float* __restrict__ Whh_in,
                         unsigned short* __restrict__ Wx, unsigned short* __restrict__ Whh){
  int jp = blockIdx.x;
  int g = jp & 3, kr = jp >> 2;
  int j = g * NH + kr;
  int k = threadIdx.x * 4;
  float4 a = *(const float4*)(Wih + (size_t)j * (ND + NT) + k);
  float4 b = *(const float4*)(Whh_in + ((size_t)j << 10) + k);
  unsigned short* d1 = Wx + ((size_t)jp << 10) + k;
  unsigned short* d2 = Whh + ((size_t)jp << 10) + k;
  d1[0] = f2bf(a.x); d1[1] = f2bf(a.y); d1[2] = f2bf(a.z); d1[3] = f2bf(a.w);
  d2[0] = f2bf(b.x); d2[1] = f2bf(b.y); d2[2] = f2bf(b.z); d2[3] = f2bf(b.w);
}

__global__ void k_prep_tb(const float* __restrict__ Wih, const float* __restrict__ bih,
                          const float* __restrict__ bhh, float* __restrict__ Wtag,
                          float* __restrict__ biasc){
  int blk = blockIdx.x;
  for (int jp = threadIdx.x; jp < NG; jp += 256){
    int g = jp & 3, kr = jp >> 2;
    int j = g * NH + kr;
    if (blk < NT) Wtag[(size_t)blk * NG + jp] = Wih[(size_t)j * (ND + NT) + ND + blk];
    else          biasc[jp] = bih[j] + bhh[j];
  }
}

__global__ void k_prep_state(float* c, unsigned short* hb0, unsigned short* hb1,
                             float* logits, const float* __restrict__ bout,
                             float* loss, unsigned* bar){
  int i = blockIdx.x * 256 + threadIdx.x;   // grid covers 131072
  c[i] = 0.f; hb0[i] = 0; hb1[i] = 0;
  if (i < 3 * NB * NT) logits[i] = bout[i % NT];
  if (i < 512) bar[i] = 0;
  if (i == 0) *loss = 0.f;
}

// x[b][s][d] f32 -> xb[(s*128+b)][d] bf16
__global__ void k_xpose(const float* __restrict__ x, unsigned short* __restrict__ xb){
  int r = blockIdx.x;
  int b = r & 127, s = r >> 7;
  int d = threadIdx.x * 4;
  float4 v = *(const float4*)(x + (((size_t)b * NS + s) << 10) + d);
  unsigned short* o = xb + ((size_t)r << 10) + d;
  o[0] = f2bf(v.x); o[1] = f2bf(v.y); o[2] = f2bf(v.z); o[3] = f2bf(v.w);
}

// ---------------- Gx precompute GEMM ----------------
__global__ __launch_bounds__(256, 2) void k_gemm_gx(const unsigned short* __restrict__ xb,
                                                    const unsigned short* __restrict__ Wx,
                                                    unsigned short* __restrict__ Gx, int row0){
  __shared__ unsigned short At[128 * 32];
  __shared__ unsigned short Bt[128 * 32];
  const int tid = threadIdx.x;
  const int wave = tid >> 6, lane = tid & 63;
  const int l15 = lane & 15, l4 = lane >> 4;
  const int wm = wave >> 1, wn = wave & 1;
  const int mloc = (int)blockIdx.x * 128;
  const int n0 = (int)blockIdx.y * 128;
  const unsigned short* Ab = xb + ((size_t)(row0 + mloc) << 10);
  const unsigned short* Bb = Wx + ((size_t)n0 << 10);

  v4f acc[4][4];
#pragma unroll
  for (int i = 0; i < 4; ++i)
#pragma unroll
    for (int j = 0; j < 4; ++j) acc[i][j] = (v4f){0.f, 0.f, 0.f, 0.f};

  for (int kk = 0; kk < 32; ++kk){
    const int k0 = kk * 32;
#pragma unroll
    for (int is = 0; is < 2; ++is){
      int c = is * 256 + tid;
      gload16(Ab + ((size_t)(c >> 2) << 10) + k0 + (c & 3) * 8, At + (is * 256 + wave * 64) * 8);
      gload16(Bb + ((size_t)(c >> 2) << 10) + k0 + (c & 3) * 8, Bt + (is * 256 + wave * 64) * 8);
    }
    __syncthreads();
    v8bf af[4], bfm[4];
#pragma unroll
    for (int i = 0; i < 4; ++i) af[i]  = *(const v8bf*)(At + (wm * 64 + i * 16 + l15) * 32 + l4 * 8);
#pragma unroll
    for (int j = 0; j < 4; ++j) bfm[j] = *(const v8bf*)(Bt + (wn * 64 + j * 16 + l15) * 32 + l4 * 8);
#pragma unroll
    for (int i = 0; i < 4; ++i)
#pragma unroll
      for (int j = 0; j < 4; ++j) acc[i][j] = mfma16x16x32(af[i], bfm[j], acc[i][j]);
    __syncthreads();
  }
#pragma unroll
  for (int i = 0; i < 4; ++i)
#pragma unroll
    for (int j = 0; j < 4; ++j){
      int r = mloc + wm * 64 + i * 16 + l4 * 4;
      int cc = n0 + wn * 64 + j * 16 + l15;
#pragma unroll
      for (int q = 0; q < 4; ++q) Gx[((size_t)(r + q) << 12) + cc] = f2bf(acc[i][j][q]);
    }
}

// ---------------- persistent cooperative step kernel ----------------

struct StepArgs {
  const unsigned short* Whh;   // [4096][1024] bf16 permuted (j' = 4k+gate)
  const unsigned short* Gx;    // [nsteps*128][4096] bf16
  const float* Wtag;           // [20][4096]
  const float* biasc;          // [4096]
  const float* Wout;           // [20][1024] f32
  const float* bout;           // [20]
  const int* tags;             // [128][256]
  const int* mask;             // [128][256]
  unsigned short* hb0;         // [128][1024] bf16 parity buffers
  unsigned short* hb1;
  float* c;                    // [128][1024] f32 (chunk-boundary spill only)
  float* logits;               // [3][128][20] f32 rotating
  float* loss;
  unsigned* bar;
  int s0, nsteps;
};

// 256 wgs (1/CU), 512 threads. wg (bi,ni): 32 batch rows x 64 gate cols, K=1024.
__global__ __launch_bounds__(512, 1) void k_step(StepArgs A){
  __shared__ unsigned short Wsl[64 * 1024];   // 128 KB persistent W_hh slice
  __shared__ float sH[32][17];
  __shared__ float sWo[NT][16];
  __shared__ int sPt[32];
  const int tid = threadIdx.x;
  const int wave = tid >> 6, lane = tid & 63;
  const int l15 = lane & 15, l4 = lane >> 4;
  const int wm = wave >> 2, wn = wave & 3;
  const int bi = (int)blockIdx.x >> 6;
  const int ni = (int)blockIdx.x & 63;
  const int b0 = bi * 32;
  const int n0 = ni * 64;

  // stage W_hh slice (XOR-swizzled) + Wout slice
  for (int ch = tid; ch < 64 * 128; ch += 512){
    int jl = ch >> 7, kc = ch & 127;
    v8bf v = *(const v8bf*)(A.Whh + ((size_t)(n0 + jl) << 10) + kc * 8);
    *(v8bf*)((char*)Wsl + ((size_t)jl << 11) +
             (((unsigned)(kc << 4)) ^ ((unsigned)((jl & 7) << 4)))) = v;
  }
  if (tid < NT * 16){
    int t = tid >> 4, kl = tid & 15;
    sWo[t][kl] = A.Wout[t * NH + (n0 >> 2) + kl];
  }
  __syncthreads();

  const int jl_f = wn * 16 + l15;
  const char* wbase = (const char*)Wsl + ((size_t)jl_f << 11);
  const unsigned sw = (unsigned)((jl_f & 7) << 4);
  const int jcol = n0 + jl_f;
  const int kh = jcol >> 2;
  const int bb = b0 + wm * 16 + l4 * 4;
  const float gb = A.biasc[jcol];
  const int qb = lane & ~3;
  const int bloc = wm * 16 + l4 * 4;        // b_local base
  const int khl = wn * 4 + (l15 >> 2);      // kh_local (valid on quad-lane-0)

  float creg[4];
  if ((lane & 3) == 0){
#pragma unroll
    for (int q = 0; q < 4; ++q) creg[q] = A.c[((size_t)(bb + q) << 10) + kh];
  }
  float lacc = 0.f;

  for (int sl = 0; sl < A.nsteps; ++sl){
    const int s = A.s0 + sl;
    const int m  = s % 3;
    const int m1 = (s + 2) % 3;
    const int mz = (s + 1) % 3;
    const unsigned short* hr = (s & 1) ? A.hb1 : A.hb0;
    unsigned short* hw = (s & 1) ? A.hb0 : A.hb1;

    // prefetch Gx (independent of recurrent state)
    const unsigned short* gxs = A.Gx + (size_t)sl * NB * NG + jcol;
    float gxv[4];
#pragma unroll
    for (int q = 0; q < 4; ++q) gxv[q] = bf2f(gxs[(size_t)(bb + q) * NG]);

    // redundant per-wg argmax -> sPt (prev tags)
    if (tid < 32){
      int pt = START_IDX_;
      if (s > 0){
        const float* lr = A.logits + ((size_t)m1 * NB + b0 + tid) * NT;
        float mv = lr[0]; pt = 0;
#pragma unroll
        for (int t = 1; t < NT; ++t){ float v = lr[t]; if (v > mv){ mv = v; pt = t; } }
      }
      sPt[tid] = pt;
    }

    // designated wgs pre-fill buffer mz with b_out (race-free: mz idle this step)
    if (ni == 32){
      for (int idx = tid; idx < 32 * NT; idx += 512){
        int b = idx / NT, t = idx - b * NT;
        A.logits[((size_t)mz * NB + b0 + b) * NT + t] = A.bout[t];
      }
    }

    // gates GEMM: h(s-1) @ Whh_slice^T
    v4f acc = {0.f, 0.f, 0.f, 0.f};
    const unsigned short* hrow = hr + ((size_t)(b0 + wm * 16 + l15) << 10) + l4 * 8;
#pragma unroll 4
    for (int kk = 0; kk < 32; ++kk){
      v8bf a = *(const v8bf*)(hrow + kk * 32);
      v8bf b = *(const v8bf*)(wbase + (((unsigned)(kk * 64 + l4 * 16)) ^ sw));
      acc = mfma16x16x32(a, b, acc);
    }
    __syncthreads();   // sPt ready

    float gv[4];
#pragma unroll
    for (int q = 0; q < 4; ++q){
      int pt = sPt[bloc + q];
      gv[q] = acc[q] + gb + gxv[q] + A.Wtag[(size_t)pt * NG + jcol];
    }
#pragma unroll
    for (int q = 0; q < 4; ++q){
      float iv = __shfl(gv[q], qb + 0);
      float fv = __shfl(gv[q], qb + 1);
      float gg = __shfl(gv[q], qb + 2);
      float ov = __shfl(gv[q], qb + 3);
      if ((lane & 3) == 0){
        float cn = sigm(fv) * creg[q] + sigm(iv) * tanhf_(gg);
        float hn = sigm(ov) * tanhf_(cn);
        creg[q] = cn;
        hw[((size_t)(bb + q) << 10) + kh] = f2bf(hn);
        sH[bloc + q][khl] = hn;
      }
    }
    __syncthreads();   // sH complete

    // logits partials: 640 (t,b) pairs, dot over this wg's 16 k's
    for (int idx = tid; idx < 32 * NT; idx += 512){
      int t = idx >> 5, b = idx & 31;
      float p = 0.f;
#pragma unroll
      for (int k = 0; k < 16; ++k) p += sH[b][k] * sWo[t][k];
      atomicAdd(A.logits + ((size_t)m * NB + b0 + b) * NT + t, p);
    }

    // designated wgs: CE loss for step s-1 (register-accumulated)
    if (ni == 16 && tid < 32 && s > 0){
      int b = b0 + tid;
      int tg = A.tags[(size_t)b * NS + (s - 1)];
      int mk = A.mask[(size_t)b * NS + (s - 1)];
      if (mk != 0){
        const float* lr = A.logits + ((size_t)m1 * NB + b) * NT;
        float mv = lr[0];
#pragma unroll
        for (int t = 1; t < NT; ++t) mv = fmaxf(mv, lr[t]);
        float se = 0.f;
#pragma unroll
        for (int t = 0; t < NT; ++t) se += __expf(lr[t] - mv);
        lacc += mv + __logf(se) - lr[tg];
      }
    }

    gridbar(A.bar, (unsigned)(s + 1));
  }

  // epilogue: spill c for chunk boundary, flush loss once
  if ((lane & 3) == 0){
#pragma unroll
    for (int q = 0; q < 4; ++q) A.c[((size_t)(bb + q) << 10) + kh] = creg[q];
  }
  if (ni == 16 && tid < 32) atomicAdd(A.loss, lacc);
}

// final: loss for last step + total
__global__ void k_final(const float* __restrict__ logits, const int* __restrict__ tags,
                        const int* __restrict__ mask, const float* __restrict__ loss,
                        float* __restrict__ out){
  __shared__ float red[NB];
  int b = threadIdx.x;
  const int s = NS - 1;
  const float* lr = logits + ((size_t)(s % 3) * NB + b) * NT;
  float v = 0.f;
  int tg = tags[(size_t)b * NS + s];
  int mk = mask[(size_t)b * NS + s];
  if (mk != 0){
    float mv = lr[0];
    for (int t = 1; t < NT; ++t) mv = fmaxf(mv, lr[t]);
    float se = 0.f;
    for (int t = 0; t < NT; ++t) se += __expf(lr[t] - mv);
    v = mv + __logf(se) - lr[tg];
  }
  red[b] = v;
  __syncthreads();
  if (b == 0){
    float tot = *loss;
    for (int i = 0; i < NB; ++i) tot += red[i];
    out[0] = tot;
  }
}

// ---------------- host ----------------

extern "C" void kernel_launch(void* const* d_in, const int* in_sizes, int n_in,
                              void* d_out, int out_size, void* d_ws, size_t ws_size,
                              hipStream_t stream){
  const float* x      = (const float*)d_in[0];
  const int*   tags   = (const int*)  d_in[1];
  const int*   mask   = (const int*)  d_in[2];
  const float* Wih    = (const float*)d_in[3];
  const float* Whh_in = (const float*)d_in[4];
  const float* bih    = (const float*)d_in[5];
  const float* bhh    = (const float*)d_in[6];
  const float* Wout   = (const float*)d_in[7];
  const float* bout   = (const float*)d_in[8];

  char* base = (char*)d_ws;
  size_t off = 0;
  auto alloc = [&](size_t bytes) -> char* {
    char* p = base + off;
    off = (off + bytes + 255) & ~(size_t)255;
    return p;
  };
  unsigned short* Wx    = (unsigned short*)alloc((size_t)NG * NH * 2);
  unsigned short* Whh   = (unsigned short*)alloc((size_t)NG * NH * 2);
  float*          Wtag  = (float*)alloc((size_t)NT * NG * 4);
  float*          biasc = (float*)alloc((size_t)NG * 4);
  unsigned short* hb0   = (unsigned short*)alloc((size_t)NB * NH * 2);
  unsigned short* hb1   = (unsigned short*)alloc((size_t)NB * NH * 2);
  float*          c     = (float*)alloc((size_t)NB * NH * 4);
  float*          logits= (float*)alloc((size_t)3 * NB * NT * 4);
  float*          loss  = (float*)alloc(256);
  unsigned*       bar   = (unsigned*)alloc(2048);
  unsigned short* xb    = (unsigned short*)alloc((size_t)NS * NB * NH * 2);

  size_t fixed = off;
  int schunk = NS;
  while (schunk > 1 && fixed + (size_t)schunk * NB * NG * 2 > ws_size) schunk >>= 1;
  unsigned short* Gx = (unsigned short*)alloc((size_t)schunk * NB * NG * 2);

  k_prep_w<<<NG, 256, 0, stream>>>(Wih, Whh_in, Wx, Whh);
  k_prep_tb<<<NT + 1, 256, 0, stream>>>(Wih, bih, bhh, Wtag, biasc);
  k_prep_state<<<(NB * NH) / 256, 256, 0, stream>>>(c, hb0, hb1, logits, bout, loss, bar);
  k_xpose<<<NS * NB, 256, 0, stream>>>(x, xb);

  int done = 0;
  while (done < NS){
    int ns = (NS - done < schunk) ? (NS - done) : schunk;
    k_gemm_gx<<<dim3(ns, 32), 256, 0, stream>>>(xb, Wx, Gx, done * NB);
    StepArgs sa;
    sa.Whh = Whh; sa.Gx = Gx; sa.Wtag = Wtag; sa.biasc = biasc;
    sa.Wout = Wout; sa.bout = bout; sa.tags = tags; sa.mask = mask;
    sa.hb0 = hb0; sa.hb1 = hb1; sa.c = c; sa.logits = logits;
    sa.loss = loss; sa.bar = bar; sa.s0 = done; sa.nsteps = ns;
    void* kargs[] = { &sa };
    hipLaunchCooperativeKernel((void*)k_step, dim3(NBLK), dim3(512), kargs, 0, stream);
    done += ns;
  }
  k_final<<<1, NB, 0, stream>>>(logits, tags, mask, loss, (float*)d_out);
}